// Round 8
// baseline (1189.907 us; speedup 1.0000x reference)
//
#include <hip/hip_runtime.h>
#include <math.h>
#include <stdint.h>

// Problem dims
#define NB 16384    // batch
#define NH 768      // hidden
#define ND 784      // input features
#define NC 10       // classes
#define NW 12       // u64 words per 768-bit row

// ---------------------------------------------------------------------------
// prep: BN params in FAITHFUL f32 (replicating np op-by-op):
// sc = g * (1 / sqrt(v + 1e-5)), each op f32-rounded. [0]=sc,[1]=m,[2]=be,[3]=bias
// ---------------------------------------------------------------------------
__global__ void k_bnprep_f32(const float* __restrict__ g, const float* __restrict__ be,
                             const float* __restrict__ m, const float* __restrict__ v,
                             const float* __restrict__ bias, float* __restrict__ out) {
    int i = blockIdx.x * 256 + threadIdx.x;
    if (i >= NH) return;
    float t1 = __fadd_rn(v[i], 1e-5f);
    float t2 = __fsqrt_rn(t1);
    float t3 = __fdiv_rn(1.0f, t2);
    out[i]          = __fmul_rn(g[i], t3);
    out[NH + i]     = m[i];
    out[2 * NH + i] = be[i];
    out[3 * NH + i] = bias[i];
}

// ---------------------------------------------------------------------------
// prep: W1 signs as bf16 +/-1 bit patterns (0x3F80 / 0xBF80), row-major [col][k]
// ---------------------------------------------------------------------------
__global__ void k_pack_w1bf(const float* __restrict__ W1, unsigned short* __restrict__ wbf) {
    int k = blockIdx.x * 256 + threadIdx.x;
    int col = blockIdx.y;
    if (k >= ND) return;
    float v = W1[(size_t)col * ND + k];
    wbf[(size_t)col * ND + k] = (v >= 0.0f) ? (unsigned short)0x3F80 : (unsigned short)0xBF80;
}

// ---------------------------------------------------------------------------
// prep: W2/W3 sign bits, transposed words: wT[j*768 + col] bit l = (W[col][j*64+l] >= 0)
// ---------------------------------------------------------------------------
__global__ void k_pack_wT(const float* __restrict__ W, unsigned long long* __restrict__ wT) {
    int idx = blockIdx.x * 256 + threadIdx.x;
    if (idx >= NH * NW) return;
    int col = idx / NW, j = idx % NW;
    unsigned long long w = 0ull;
    for (int l = 0; l < 64; ++l) {
        float v = W[(size_t)col * NH + j * 64 + l];
        w |= (unsigned long long)(v >= 0.0f ? 1 : 0) << l;
    }
    wT[(size_t)j * NH + col] = w;
}

// ---------------------------------------------------------------------------
// GEMM1 replicating numpy einsum sum_of_products_contig_two (AVX512 npyv).
// R8 restructure: each output's 64-acc einsum state is SPLIT across 2 threads
// by j-half (32 accs each) -> no spills (R6/R7: VGPR_Count=64 + ~250 MB
// scratch WRITE). Tree level h8[i]=v[i]+v[i+8] is a shfl_xor(32) pair-sum
// (IEEE add commutative -> both partners bit-identical); rest in-thread.
// Chain order EXACT: a[g][i] accumulates k = t*64+g*16+(j0+i), t ascending,
// tail k=768.. into group 0, combine (a0+a1)+(a2+a3), tree 8/4/2/1.
// Block: 512 thr = 8 waves; wave = 1 row; lane = colsub(0..31) + 32*jh.
// Grid: (NB/8, NH/32). LDS 77 KB -> 2 blocks/CU.
// ---------------------------------------------------------------------------
__global__ __launch_bounds__(512, 4)
void k_gemm1_bf(const float* __restrict__ x, const unsigned short* __restrict__ wbf,
                const float* __restrict__ bnp,
                unsigned int* __restrict__ s1p32) {
    __shared__ float xs[8][ND];                         // 25,088 B
    __shared__ alignas(16) unsigned short wl[32][808];  // 51,712 B (pitch 1616 B)
    const int tid = threadIdx.x;
    const int r0 = blockIdx.x * 8;
    const int c0 = blockIdx.y * 32;

    // stage x: 8 rows x 784 f32
    for (int d = tid; d < 8 * ND; d += 512) {
        int r = d / ND, k = d % ND;
        xs[r][k] = x[(size_t)(r0 + r) * ND + k];
    }
    // stage w: 32 cols x 784 bf16 (392 dwords per col); 16 threads per col
    {
        const unsigned int* wsrc = (const unsigned int*)wbf;
        int c = tid >> 4;          // 0..31
        int q = tid & 15;
        unsigned int* dst = (unsigned int*)&wl[c][0];
        const unsigned int* srcp = wsrc + (size_t)(c0 + c) * 392;
        for (int k2 = q; k2 < 392; k2 += 16) dst[k2] = srcp[k2];
    }
    __syncthreads();

    const int wave = tid >> 6, lane = tid & 63;
    const int colsub = lane & 31, jh = lane >> 5;
    const int j0 = jh * 8;
    const unsigned short* wrow = &wl[colsub][j0];
    const float* xrow = &xs[wave][j0];

    float a[4][8];
#pragma unroll
    for (int g = 0; g < 4; ++g)
#pragma unroll
        for (int i = 0; i < 8; ++i) a[g][i] = 0.0f;

    // main loop: t = 0..11, each covers k = t*64 .. t*64+63
    for (int t = 0; t < 12; ++t) {
#pragma unroll
        for (int g = 0; g < 4; ++g) {
            const int kk = t * 64 + g * 16;
            uint4 wA = *(const uint4*)(wrow + kk);       // 8 bf16: k = kk+j0 .. +7
            float4 x0 = *(const float4*)(xrow + kk);
            float4 x1 = *(const float4*)(xrow + kk + 4);
            unsigned int dw[4] = {wA.x, wA.y, wA.z, wA.w};
            float wf[8];
#pragma unroll
            for (int p = 0; p < 4; ++p) {
                wf[2 * p]     = __uint_as_float(dw[p] << 16);          // low bf16 -> f32
                wf[2 * p + 1] = __uint_as_float(dw[p] & 0xFFFF0000u);  // high bf16 -> f32
            }
            float xv[8] = {x0.x, x0.y, x0.z, x0.w, x1.x, x1.y, x1.z, x1.w};
#pragma unroll
            for (int i = 0; i < 8; ++i)
                a[g][i] = __fmaf_rn(wf[i], xv[i], a[g][i]);
        }
    }
    // single-vector tail: k = 768..783 into group 0
    {
        const int kk = 768;
        uint4 wA = *(const uint4*)(wrow + kk);
        float4 x0 = *(const float4*)(xrow + kk);
        float4 x1 = *(const float4*)(xrow + kk + 4);
        unsigned int dw[4] = {wA.x, wA.y, wA.z, wA.w};
        float wf[8];
#pragma unroll
        for (int p = 0; p < 4; ++p) {
            wf[2 * p]     = __uint_as_float(dw[p] << 16);
            wf[2 * p + 1] = __uint_as_float(dw[p] & 0xFFFF0000u);
        }
        float xv[8] = {x0.x, x0.y, x0.z, x0.w, x1.x, x1.y, x1.z, x1.w};
#pragma unroll
        for (int i = 0; i < 8; ++i)
            a[0][i] = __fmaf_rn(wf[i], xv[i], a[0][i]);
    }

    // combine: v[i] = (a0+a1)+(a2+a3) lane-wise (this thread's 8 j-lanes)
    float v[8];
#pragma unroll
    for (int i = 0; i < 8; ++i)
        v[i] = __fadd_rn(__fadd_rn(a[0][i], a[1][i]), __fadd_rn(a[2][i], a[3][i]));
    // tree level 1: h8[i] = v[i] + v[i+8]  (pair-exchange with jh-partner)
    float h8[8];
#pragma unroll
    for (int i = 0; i < 8; ++i) {
        float other = __shfl_xor(v[i], 32, 64);
        h8[i] = __fadd_rn(v[i], other);
    }
    // remaining tree: 4/2/1
    float h4[4], h2[2];
#pragma unroll
    for (int i = 0; i < 4; ++i) h4[i] = __fadd_rn(h8[i], h8[i + 4]);
#pragma unroll
    for (int i = 0; i < 2; ++i) h2[i] = __fadd_rn(h4[i], h4[i + 2]);
    float acc = __fadd_rn(h2[0], h2[1]);

    // epilogue: + b1, BN1 f32 op-by-op, sign -> packed bits (u32 half-word)
    const int col = c0 + colsub;
    const float sc = bnp[col], mm = bnp[NH + col], be = bnp[2 * NH + col],
                bias = bnp[3 * NH + col];
    float h  = __fadd_rn(acc, bias);
    float t1 = __fsub_rn(h, mm);
    float u  = __fmul_rn(t1, sc);
    float hb = __fadd_rn(u, be);
    unsigned long long word = __ballot(hb >= 0.0f);   // bits 0..31 = cols (jh=0 lanes)
    if (lane == 0)
        s1p32[(size_t)(r0 + wave) * (2 * NW) + blockIdx.y] = (unsigned int)word;
}

// ---------------------------------------------------------------------------
// Binary layers 2/3: dot = 768 - 2*popcount(a XOR w) — exact integer, matches
// any-order f32 evaluation of +/-1 GEMM bit-for-bit (all partials exact).
// Epilogue faithful f32: h = fl(dot + b), BN op-by-op.
// MODE 0: sign -> packed bits. MODE 1: hardtanh -> f32 out.
// ---------------------------------------------------------------------------
template <int MODE>
__global__ __launch_bounds__(256, 2)
void k_popbin(const unsigned long long* __restrict__ Ap,
              const unsigned long long* __restrict__ wT,
              const float* __restrict__ bnp,
              unsigned long long* __restrict__ Sp, float* __restrict__ h_out) {
    __shared__ unsigned long long as[64][NW];
    const int tid = threadIdx.x;
    const int b0 = blockIdx.x * 64;

    for (int i = tid; i < 64 * NW; i += 256)
        as[i / NW][i % NW] = Ap[(size_t)(b0 + i / NW) * NW + i % NW];
    __syncthreads();

    const int wave = tid >> 6, lane = tid & 63;

    for (int chunk = 0; chunk < NW; ++chunk) {
        const int col = chunk * 64 + lane;
        unsigned long long w[NW];
#pragma unroll
        for (int j = 0; j < NW; ++j) w[j] = wT[(size_t)j * NH + col];
        const float sc = bnp[col], mm = bnp[NH + col], be = bnp[2 * NH + col],
                    bias = bnp[3 * NH + col];
        for (int r = 0; r < 16; ++r) {
            const int row = wave * 16 + r;
            int d = 0;
#pragma unroll
            for (int j = 0; j < NW; ++j)
                d += __builtin_popcountll(as[row][j] ^ w[j]);
            int dot = NH - 2 * d;
            float h  = __fadd_rn((float)dot, bias);
            float t  = __fsub_rn(h, mm);
            float u  = __fmul_rn(t, sc);
            float hb = __fadd_rn(u, be);
            if (MODE == 0) {
                unsigned long long word = __ballot(hb >= 0.0f);
                if (lane == 0) Sp[(size_t)(b0 + row) * NW + chunk] = word;
            } else {
                float hc = fminf(fmaxf(hb, -1.0f), 1.0f);
                h_out[(size_t)(b0 + row) * NH + col] = hc;
            }
        }
    }
}

// ---------------------------------------------------------------------------
// fc4 + log_softmax: one wave per row, double accumulation + shuffle reduce
// (no binarization downstream; 1e-6-level diffs vs f32 ref are far under threshold)
// ---------------------------------------------------------------------------
__global__ __launch_bounds__(256, 4)
void k_fc4(const float* __restrict__ h3, const float* __restrict__ W4,
           const float* __restrict__ b4, float* __restrict__ out) {
    __shared__ float w4s[NC * NH];
    const int tid = threadIdx.x;
    for (int i = tid; i < NC * NH; i += 256) w4s[i] = W4[i];
    __syncthreads();

    const int wave = tid >> 6, lane = tid & 63;
    const int row = blockIdx.x * 4 + wave;
    const float* hrow = h3 + (size_t)row * NH;

    double p[NC];
#pragma unroll
    for (int c = 0; c < NC; ++c) p[c] = 0.0;

    for (int it = 0; it < NH / 64; ++it) {
        int j = it * 64 + lane;
        double hv = (double)hrow[j];
#pragma unroll
        for (int c = 0; c < NC; ++c) p[c] += hv * (double)w4s[c * NH + j];
    }
#pragma unroll
    for (int c = 0; c < NC; ++c) {
#pragma unroll
        for (int off = 32; off > 0; off >>= 1) p[c] += __shfl_xor(p[c], off, 64);
    }
    double lg[NC];
    double mx = -1e300;
#pragma unroll
    for (int c = 0; c < NC; ++c) {
        lg[c] = p[c] + (double)b4[c];
        mx = fmax(mx, lg[c]);
    }
    double s = 0.0;
#pragma unroll
    for (int c = 0; c < NC; ++c) s += exp(lg[c] - mx);
    double lse = mx + log(s);
    if (lane < NC) {
        double v = 0.0;
#pragma unroll
        for (int c = 0; c < NC; ++c)
            if (lane == c) v = lg[c];
        out[(size_t)row * NC + lane] = (float)(v - lse);
    }
}

// ---------------------------------------------------------------------------
// launch
// ---------------------------------------------------------------------------
extern "C" void kernel_launch(void* const* d_in, const int* in_sizes, int n_in,
                              void* d_out, int out_size, void* d_ws, size_t ws_size,
                              hipStream_t stream) {
    const float* x  = (const float*)d_in[0];
    const float* W1 = (const float*)d_in[1];
    const float* b1 = (const float*)d_in[2];
    const float* W2 = (const float*)d_in[3];
    const float* b2 = (const float*)d_in[4];
    const float* W3 = (const float*)d_in[5];
    const float* b3 = (const float*)d_in[6];
    const float* W4 = (const float*)d_in[7];
    const float* b4 = (const float*)d_in[8];
    const float* g1 = (const float*)d_in[9],  *be1 = (const float*)d_in[10];
    const float* m1 = (const float*)d_in[11], *v1  = (const float*)d_in[12];
    const float* g2 = (const float*)d_in[13], *be2 = (const float*)d_in[14];
    const float* m2 = (const float*)d_in[15], *v2  = (const float*)d_in[16];
    const float* g3 = (const float*)d_in[17], *be3 = (const float*)d_in[18];
    const float* m3 = (const float*)d_in[19], *v3  = (const float*)d_in[20];
    float* out = (float*)d_out;

    char* ws = (char*)d_ws;
    size_t off = 0;
    unsigned short* wbf = (unsigned short*)(ws + off);  off += (size_t)NH * ND * 2;   // 1,204,224
    unsigned long long* w2pT = (unsigned long long*)(ws + off); off += (size_t)NW * NH * 8;  // 73,728
    unsigned long long* w3pT = (unsigned long long*)(ws + off); off += (size_t)NW * NH * 8;
    unsigned long long* s1p  = (unsigned long long*)(ws + off); off += (size_t)NB * NW * 8;  // 1,572,864
    unsigned long long* s2p  = (unsigned long long*)(ws + off); off += (size_t)NB * NW * 8;
    float*  h3   = (float*)(ws + off);              off += (size_t)NB * NH * 4;       // 50,331,648
    float* bnp1 = (float*)(ws + off);               off += (size_t)4 * NH * 4;
    float* bnp2 = (float*)(ws + off);               off += (size_t)4 * NH * 4;
    float* bnp3 = (float*)(ws + off);               off += (size_t)4 * NH * 4;
    (void)ws_size; (void)in_sizes; (void)n_in; (void)out_size;

    // prep
    k_pack_w1bf<<<dim3(4, NH), 256, 0, stream>>>(W1, wbf);
    k_pack_wT<<<dim3((NH * NW + 255) / 256), 256, 0, stream>>>(W2, w2pT);
    k_pack_wT<<<dim3((NH * NW + 255) / 256), 256, 0, stream>>>(W3, w3pT);
    k_bnprep_f32<<<dim3(3), 256, 0, stream>>>(g1, be1, m1, v1, b1, bnp1);
    k_bnprep_f32<<<dim3(3), 256, 0, stream>>>(g2, be2, m2, v2, b2, bnp2);
    k_bnprep_f32<<<dim3(3), 256, 0, stream>>>(g3, be3, m3, v3, b3, bnp3);

    // layers
    k_gemm1_bf<<<dim3(NB / 8, NH / 32), 512, 0, stream>>>(x, wbf, bnp1,
                                                          (unsigned int*)s1p);
    k_popbin<0><<<dim3(NB / 64), 256, 0, stream>>>(s1p, w2pT, bnp2, s2p, nullptr);
    k_popbin<1><<<dim3(NB / 64), 256, 0, stream>>>(s2p, w3pT, bnp3, nullptr, h3);
    k_fc4<<<dim3(NB / 4), 256, 0, stream>>>(h3, W4, b4, out);
}

// Round 9
// 882.644 us; speedup vs baseline: 1.3481x; 1.3481x over previous
//
#include <hip/hip_runtime.h>
#include <math.h>
#include <stdint.h>

// Problem dims
#define NB 16384    // batch
#define NH 768      // hidden
#define ND 784      // input features
#define NC 10       // classes
#define NW 12       // u64 words per 768-bit row

// ---------------------------------------------------------------------------
// prep: BN params in FAITHFUL f32 (replicating np op-by-op):
// sc = g * (1 / sqrt(v + 1e-5)), each op f32-rounded. [0]=sc,[1]=m,[2]=be,[3]=bias
// ---------------------------------------------------------------------------
__global__ void k_bnprep_f32(const float* __restrict__ g, const float* __restrict__ be,
                             const float* __restrict__ m, const float* __restrict__ v,
                             const float* __restrict__ bias, float* __restrict__ out) {
    int i = blockIdx.x * 256 + threadIdx.x;
    if (i >= NH) return;
    float t1 = __fadd_rn(v[i], 1e-5f);
    float t2 = __fsqrt_rn(t1);
    float t3 = __fdiv_rn(1.0f, t2);
    out[i]          = __fmul_rn(g[i], t3);
    out[NH + i]     = m[i];
    out[2 * NH + i] = be[i];
    out[3 * NH + i] = bias[i];
}

// ---------------------------------------------------------------------------
// prep: W1 signs as bf16 +/-1 bit patterns (0x3F80 / 0xBF80), row-major [col][k]
// ---------------------------------------------------------------------------
__global__ void k_pack_w1bf(const float* __restrict__ W1, unsigned short* __restrict__ wbf) {
    int k = blockIdx.x * 256 + threadIdx.x;
    int col = blockIdx.y;
    if (k >= ND) return;
    float v = W1[(size_t)col * ND + k];
    wbf[(size_t)col * ND + k] = (v >= 0.0f) ? (unsigned short)0x3F80 : (unsigned short)0xBF80;
}

// ---------------------------------------------------------------------------
// prep: W2/W3 sign bits, transposed words: wT[j*768 + col] bit l = (W[col][j*64+l] >= 0)
// ---------------------------------------------------------------------------
__global__ void k_pack_wT(const float* __restrict__ W, unsigned long long* __restrict__ wT) {
    int idx = blockIdx.x * 256 + threadIdx.x;
    if (idx >= NH * NW) return;
    int col = idx / NW, j = idx % NW;
    unsigned long long w = 0ull;
    for (int l = 0; l < 64; ++l) {
        float v = W[(size_t)col * NH + j * 64 + l];
        w |= (unsigned long long)(v >= 0.0f ? 1 : 0) << l;
    }
    wT[(size_t)j * NH + col] = w;
}

// ---------------------------------------------------------------------------
// GEMM1 replicating numpy einsum sum_of_products_contig_two (AVX512 npyv).
// Thread = (row=wave, colsub=lane&31, jh=lane>>5): 32 accs, no spills.
// Chain order EXACT: a[g][i] accumulates k = t*64+g*16+(jh*8+i), t ascending,
// tail k=768.. into group 0, combine (a0+a1)+(a2+a3), tree 8/4/2/1
// (level-1 pair-sum via shfl_xor(32); IEEE add commutative -> bit-identical).
// R9 vs R8 (math identical):
//  - staging is division-free: wave stages its own x row as float4;
//    w-tile staged as uint4 (was: / and % -> ~500 hidden VALU instr/wave)
//  - 2 col-tiles per block reuse the staged x (FETCH was doubled in R8)
//  - t-loop fully unrolled (constant ds_read offsets)
// Block: 512 thr = 8 waves; grid (NB/8, NH/64); LDS 77 KB -> 2 blocks/CU.
// ---------------------------------------------------------------------------
__global__ __launch_bounds__(512, 4)
void k_gemm1_bf(const float* __restrict__ x, const unsigned short* __restrict__ wbf,
                const float* __restrict__ bnp,
                unsigned int* __restrict__ s1p32) {
    __shared__ float xs[8][ND];                         // 25,088 B
    __shared__ alignas(16) unsigned short wl[32][808];  // 51,712 B (pitch 1616 B = 101 uint4)
    const int tid = threadIdx.x;
    const int r0 = blockIdx.x * 8;
    const int wave = tid >> 6, lane = tid & 63;
    const int colsub = lane & 31, jh = lane >> 5;
    const int j0 = jh * 8;

    // stage x: wave w stages its own row (196 float4); wave-coherent, no sync needed
    {
        const float4* src = (const float4*)(x + (size_t)(r0 + wave) * ND);
        float4* dst = (float4*)&xs[wave][0];
        for (int k4 = lane; k4 < 196; k4 += 64) dst[k4] = src[k4];
    }

    const float* xrow = &xs[wave][j0];

#pragma unroll 1
    for (int tile = 0; tile < 2; ++tile) {
        const int c0 = blockIdx.y * 64 + tile * 32;
        __syncthreads();   // tile1: all waves done reading wl tile0 (also orders tile0 stage)
        // stage w: 32 cols x 98 uint4 per col; 16 threads per col
        {
            int c = tid >> 4, q = tid & 15;
            uint4* dst = (uint4*)&wl[c][0];
            const uint4* srcp = (const uint4*)(wbf + (size_t)(c0 + c) * ND);
#pragma unroll
            for (int k4 = q; k4 < 98; k4 += 16) dst[k4] = srcp[k4];
        }
        __syncthreads();

        const unsigned short* wrow = &wl[colsub][j0];

        float a[4][8];
#pragma unroll
        for (int g = 0; g < 4; ++g)
#pragma unroll
            for (int i = 0; i < 8; ++i) a[g][i] = 0.0f;

        // main loop: t = 0..11, each covers k = t*64 .. t*64+63
#pragma unroll
        for (int t = 0; t < 12; ++t) {
#pragma unroll
            for (int g = 0; g < 4; ++g) {
                const int kk = t * 64 + g * 16;
                uint4 wA = *(const uint4*)(wrow + kk);       // 8 bf16: k = kk+j0 .. +7
                float4 x0 = *(const float4*)(xrow + kk);
                float4 x1 = *(const float4*)(xrow + kk + 4);
                unsigned int dw[4] = {wA.x, wA.y, wA.z, wA.w};
                float wf[8];
#pragma unroll
                for (int p = 0; p < 4; ++p) {
                    wf[2 * p]     = __uint_as_float(dw[p] << 16);          // low bf16
                    wf[2 * p + 1] = __uint_as_float(dw[p] & 0xFFFF0000u);  // high bf16
                }
                float xv[8] = {x0.x, x0.y, x0.z, x0.w, x1.x, x1.y, x1.z, x1.w};
#pragma unroll
                for (int i = 0; i < 8; ++i)
                    a[g][i] = __fmaf_rn(wf[i], xv[i], a[g][i]);
            }
        }
        // single-vector tail: k = 768..783 into group 0
        {
            const int kk = 768;
            uint4 wA = *(const uint4*)(wrow + kk);
            float4 x0 = *(const float4*)(xrow + kk);
            float4 x1 = *(const float4*)(xrow + kk + 4);
            unsigned int dw[4] = {wA.x, wA.y, wA.z, wA.w};
            float wf[8];
#pragma unroll
            for (int p = 0; p < 4; ++p) {
                wf[2 * p]     = __uint_as_float(dw[p] << 16);
                wf[2 * p + 1] = __uint_as_float(dw[p] & 0xFFFF0000u);
            }
            float xv[8] = {x0.x, x0.y, x0.z, x0.w, x1.x, x1.y, x1.z, x1.w};
#pragma unroll
            for (int i = 0; i < 8; ++i)
                a[0][i] = __fmaf_rn(wf[i], xv[i], a[0][i]);
        }

        // combine: v[i] = (a0+a1)+(a2+a3) lane-wise (this thread's 8 j-lanes)
        float v[8];
#pragma unroll
        for (int i = 0; i < 8; ++i)
            v[i] = __fadd_rn(__fadd_rn(a[0][i], a[1][i]), __fadd_rn(a[2][i], a[3][i]));
        // tree level 1: h8[i] = v[i] + v[i+8]  (pair-exchange with jh-partner)
        float h8[8];
#pragma unroll
        for (int i = 0; i < 8; ++i) {
            float other = __shfl_xor(v[i], 32, 64);
            h8[i] = __fadd_rn(v[i], other);
        }
        // remaining tree: 4/2/1
        float h4[4], h2[2];
#pragma unroll
        for (int i = 0; i < 4; ++i) h4[i] = __fadd_rn(h8[i], h8[i + 4]);
#pragma unroll
        for (int i = 0; i < 2; ++i) h2[i] = __fadd_rn(h4[i], h4[i + 2]);
        float acc = __fadd_rn(h2[0], h2[1]);

        // epilogue: + b1, BN1 f32 op-by-op, sign -> packed bits (u32 half-word)
        const int col = c0 + colsub;
        const float sc = bnp[col], mm = bnp[NH + col], be = bnp[2 * NH + col],
                    bias = bnp[3 * NH + col];
        float h  = __fadd_rn(acc, bias);
        float t1 = __fsub_rn(h, mm);
        float u  = __fmul_rn(t1, sc);
        float hb = __fadd_rn(u, be);
        unsigned long long word = __ballot(hb >= 0.0f);   // bits 0..31 = cols (jh=0)
        if (lane == 0)
            s1p32[(size_t)(r0 + wave) * (2 * NW) + blockIdx.y * 2 + tile] =
                (unsigned int)word;
    }
}

// ---------------------------------------------------------------------------
// Binary layers 2/3: dot = 768 - 2*popcount(a XOR w) — exact integer, matches
// any-order f32 evaluation of +/-1 GEMM bit-for-bit (all partials exact).
// Epilogue faithful f32: h = fl(dot + b), BN op-by-op.
// MODE 0: sign -> packed bits. MODE 1: hardtanh -> f32 out.
// ---------------------------------------------------------------------------
template <int MODE>
__global__ __launch_bounds__(256, 2)
void k_popbin(const unsigned long long* __restrict__ Ap,
              const unsigned long long* __restrict__ wT,
              const float* __restrict__ bnp,
              unsigned long long* __restrict__ Sp, float* __restrict__ h_out) {
    __shared__ unsigned long long as[64][NW];
    const int tid = threadIdx.x;
    const int b0 = blockIdx.x * 64;

    // contiguous copy (rows x NW words are contiguous) — no div/mod
    {
        unsigned long long* asf = &as[0][0];
        const unsigned long long* src = Ap + (size_t)b0 * NW;
        for (int i = tid; i < 64 * NW; i += 256) asf[i] = src[i];
    }
    __syncthreads();

    const int wave = tid >> 6, lane = tid & 63;

    for (int chunk = 0; chunk < NW; ++chunk) {
        const int col = chunk * 64 + lane;
        unsigned long long w[NW];
#pragma unroll
        for (int j = 0; j < NW; ++j) w[j] = wT[(size_t)j * NH + col];
        const float sc = bnp[col], mm = bnp[NH + col], be = bnp[2 * NH + col],
                    bias = bnp[3 * NH + col];
        for (int r = 0; r < 16; ++r) {
            const int row = wave * 16 + r;
            int d = 0;
#pragma unroll
            for (int j = 0; j < NW; ++j)
                d += __builtin_popcountll(as[row][j] ^ w[j]);
            int dot = NH - 2 * d;
            float h  = __fadd_rn((float)dot, bias);
            float t  = __fsub_rn(h, mm);
            float u  = __fmul_rn(t, sc);
            float hb = __fadd_rn(u, be);
            if (MODE == 0) {
                unsigned long long word = __ballot(hb >= 0.0f);
                if (lane == 0) Sp[(size_t)(b0 + row) * NW + chunk] = word;
            } else {
                float hc = fminf(fmaxf(hb, -1.0f), 1.0f);
                h_out[(size_t)(b0 + row) * NH + col] = hc;
            }
        }
    }
}

// ---------------------------------------------------------------------------
// fc4 + log_softmax: one wave per row, double accumulation + shuffle reduce
// (no binarization downstream; 1e-6-level diffs vs f32 ref are far under threshold)
// ---------------------------------------------------------------------------
__global__ __launch_bounds__(256, 4)
void k_fc4(const float* __restrict__ h3, const float* __restrict__ W4,
           const float* __restrict__ b4, float* __restrict__ out) {
    __shared__ float w4s[NC * NH];
    const int tid = threadIdx.x;
    for (int i = tid; i < NC * NH; i += 256) w4s[i] = W4[i];
    __syncthreads();

    const int wave = tid >> 6, lane = tid & 63;
    const int row = blockIdx.x * 4 + wave;
    const float* hrow = h3 + (size_t)row * NH;

    double p[NC];
#pragma unroll
    for (int c = 0; c < NC; ++c) p[c] = 0.0;

    for (int it = 0; it < NH / 64; ++it) {
        int j = it * 64 + lane;
        double hv = (double)hrow[j];
#pragma unroll
        for (int c = 0; c < NC; ++c) p[c] += hv * (double)w4s[c * NH + j];
    }
#pragma unroll
    for (int c = 0; c < NC; ++c) {
#pragma unroll
        for (int off = 32; off > 0; off >>= 1) p[c] += __shfl_xor(p[c], off, 64);
    }
    double lg[NC];
    double mx = -1e300;
#pragma unroll
    for (int c = 0; c < NC; ++c) {
        lg[c] = p[c] + (double)b4[c];
        mx = fmax(mx, lg[c]);
    }
    double s = 0.0;
#pragma unroll
    for (int c = 0; c < NC; ++c) s += exp(lg[c] - mx);
    double lse = mx + log(s);
    if (lane < NC) {
        double v = 0.0;
#pragma unroll
        for (int c = 0; c < NC; ++c)
            if (lane == c) v = lg[c];
        out[(size_t)row * NC + lane] = (float)(v - lse);
    }
}

// ---------------------------------------------------------------------------
// launch
// ---------------------------------------------------------------------------
extern "C" void kernel_launch(void* const* d_in, const int* in_sizes, int n_in,
                              void* d_out, int out_size, void* d_ws, size_t ws_size,
                              hipStream_t stream) {
    const float* x  = (const float*)d_in[0];
    const float* W1 = (const float*)d_in[1];
    const float* b1 = (const float*)d_in[2];
    const float* W2 = (const float*)d_in[3];
    const float* b2 = (const float*)d_in[4];
    const float* W3 = (const float*)d_in[5];
    const float* b3 = (const float*)d_in[6];
    const float* W4 = (const float*)d_in[7];
    const float* b4 = (const float*)d_in[8];
    const float* g1 = (const float*)d_in[9],  *be1 = (const float*)d_in[10];
    const float* m1 = (const float*)d_in[11], *v1  = (const float*)d_in[12];
    const float* g2 = (const float*)d_in[13], *be2 = (const float*)d_in[14];
    const float* m2 = (const float*)d_in[15], *v2  = (const float*)d_in[16];
    const float* g3 = (const float*)d_in[17], *be3 = (const float*)d_in[18];
    const float* m3 = (const float*)d_in[19], *v3  = (const float*)d_in[20];
    float* out = (float*)d_out;

    char* ws = (char*)d_ws;
    size_t off = 0;
    unsigned short* wbf = (unsigned short*)(ws + off);  off += (size_t)NH * ND * 2;   // 1,204,224
    unsigned long long* w2pT = (unsigned long long*)(ws + off); off += (size_t)NW * NH * 8;  // 73,728
    unsigned long long* w3pT = (unsigned long long*)(ws + off); off += (size_t)NW * NH * 8;
    unsigned long long* s1p  = (unsigned long long*)(ws + off); off += (size_t)NB * NW * 8;  // 1,572,864
    unsigned long long* s2p  = (unsigned long long*)(ws + off); off += (size_t)NB * NW * 8;
    float*  h3   = (float*)(ws + off);              off += (size_t)NB * NH * 4;       // 50,331,648
    float* bnp1 = (float*)(ws + off);               off += (size_t)4 * NH * 4;
    float* bnp2 = (float*)(ws + off);               off += (size_t)4 * NH * 4;
    float* bnp3 = (float*)(ws + off);               off += (size_t)4 * NH * 4;
    (void)ws_size; (void)in_sizes; (void)n_in; (void)out_size;

    // prep
    k_pack_w1bf<<<dim3(4, NH), 256, 0, stream>>>(W1, wbf);
    k_pack_wT<<<dim3((NH * NW + 255) / 256), 256, 0, stream>>>(W2, w2pT);
    k_pack_wT<<<dim3((NH * NW + 255) / 256), 256, 0, stream>>>(W3, w3pT);
    k_bnprep_f32<<<dim3(3), 256, 0, stream>>>(g1, be1, m1, v1, b1, bnp1);
    k_bnprep_f32<<<dim3(3), 256, 0, stream>>>(g2, be2, m2, v2, b2, bnp2);
    k_bnprep_f32<<<dim3(3), 256, 0, stream>>>(g3, be3, m3, v3, b3, bnp3);

    // layers
    k_gemm1_bf<<<dim3(NB / 8, NH / 64), 512, 0, stream>>>(x, wbf, bnp1,
                                                          (unsigned int*)s1p);
    k_popbin<0><<<dim3(NB / 64), 256, 0, stream>>>(s1p, w2pT, bnp2, s2p, nullptr);
    k_popbin<1><<<dim3(NB / 64), 256, 0, stream>>>(s2p, w3pT, bnp3, nullptr, h3);
    k_fc4<<<dim3(NB / 4), 256, 0, stream>>>(h3, W4, b4, out);
}